// Round 3
// baseline (542.667 us; speedup 1.0000x reference)
//
#include <hip/hip_runtime.h>
#include <hip/hip_bf16.h>

#define T_TOK 1024
#define H_DIM 1024
#define E_NUM 64
#define I_DIM 512
#define K_TOP 8
#define TG_NUM 4
#define CAPC 512
#define RSCALE 2.5f

typedef __attribute__((ext_vector_type(8))) short bf16x8;
typedef __attribute__((ext_vector_type(4))) float f32x4;

__device__ __forceinline__ ushort f2bf(float f) {
    union { float f; unsigned u; } v; v.f = f;
    unsigned r = v.u + 0x7fffu + ((v.u >> 16) & 1u);   // RNE
    return (ushort)(r >> 16);
}
__device__ __forceinline__ unsigned pk2(float lo, float hi) {
    return (unsigned)f2bf(lo) | ((unsigned)f2bf(hi) << 16);
}
// raw barrier: LDS visibility only, no vmcnt drain (keeps weight prefetch in flight)
__device__ __forceinline__ void ldsbar() {
    asm volatile("s_waitcnt lgkmcnt(0)" ::: "memory");
    __builtin_amdgcn_s_barrier();
}

// ---------------- router (+ x -> bf16 pre-convert) ----------------
__global__ __launch_bounds__(256) void k_router(
    const float* __restrict__ x, const float* __restrict__ rw,
    ushort* __restrict__ xb,
    int* __restrict__ cnt, int* __restrict__ exp_tok,
    int* __restrict__ tslot, float* __restrict__ tw)
{
    const int t    = blockIdx.x;
    const int lane = threadIdx.x & 63;
    const int w    = threadIdx.x >> 6;

    // bf16 copy of this token row
    {
        const float4 v = *(const float4*)&x[(size_t)t * H_DIM + threadIdx.x * 4];
        ushort4 o; o.x = f2bf(v.x); o.y = f2bf(v.y); o.z = f2bf(v.z); o.w = f2bf(v.w);
        *(ushort4*)&xb[(size_t)t * H_DIM + threadIdx.x * 4] = o;
    }

    const float* xp = x + (size_t)t * H_DIM + w * 256;
    const float* wp = rw + (size_t)(w * 256) * E_NUM + lane;
    float acc = 0.f;
    #pragma unroll 8
    for (int i = 0; i < 256; ++i)
        acc += xp[i] * wp[(size_t)i * E_NUM];

    __shared__ float part[4][64];
    part[w][lane] = acc;
    __syncthreads();
    if (threadIdx.x >= 64) return;

    float logit = part[0][lane] + part[1][lane] + part[2][lane] + part[3][lane];
    float score = 1.f / (1.f + expf(-logit));

    float gm = score;
    gm = fmaxf(gm, __shfl_xor(gm, 1));
    gm = fmaxf(gm, __shfl_xor(gm, 2));
    gm = fmaxf(gm, __shfl_xor(gm, 4));
    const int myg = lane >> 3;
    int grank = 0;
    #pragma unroll
    for (int j = 0; j < 8; ++j) {
        float gj = __shfl(gm, j * 8);
        grank += (gj > gm) || (gj == gm && j < myg);
    }
    float masked = (grank < TG_NUM) ? score : 0.f;

    int erank = 0;
    for (int j = 0; j < 64; ++j) {
        float sj = __shfl(masked, j);
        erank += (sj > masked) || (sj == masked && j < lane);
    }
    const bool keep = (erank < K_TOP);

    float kv = keep ? masked : 0.f;
    kv += __shfl_xor(kv, 1);  kv += __shfl_xor(kv, 2);  kv += __shfl_xor(kv, 4);
    kv += __shfl_xor(kv, 8);  kv += __shfl_xor(kv, 16); kv += __shfl_xor(kv, 32);
    const float wgt = masked / fmaxf(kv, 1e-9f) * RSCALE;

    if (keep) {
        int slot = atomicAdd(&cnt[lane], 1);
        if (slot < CAPC) {
            exp_tok[lane * CAPC + slot] = t;
            tslot[t * K_TOP + erank] = (lane << 9) | slot;
            tw[t * K_TOP + erank]    = wgt;
        } else {
            tslot[t * K_TOP + erank] = (lane << 9);
            tw[t * K_TOP + erank]    = 0.f;
        }
    }
}

// ---------------- prefix scan of counts ----------------
__global__ void k_scan(const int* __restrict__ cnt, int* __restrict__ offs)
{
    const int lane = threadIdx.x;   // 64 threads
    int v = min(cnt[lane], CAPC);
    #pragma unroll
    for (int off = 1; off < 64; off <<= 1) {
        int u = __shfl_up(v, off);
        if (lane >= off) v += u;
    }
    offs[lane + 1] = v;
    if (lane == 0) offs[0] = 0;
}

// ---------------- GEMM 1: gate & up + SwiGLU ----------------
// grid: x = mt (2), y = I/64 (8), z = 72 (64 routed + 8 virtual shared chunks)
__global__ __launch_bounds__(512) void k_gemm1(
    const ushort* __restrict__ xb,
    const float* __restrict__ gate_w, const float* __restrict__ up_w,
    const float* __restrict__ sgate_w, const float* __restrict__ sup_w,
    const int* __restrict__ cnt, const int* __restrict__ offs,
    const int* __restrict__ exp_tok,
    ushort* __restrict__ hbuf)
{
    const int mt = blockIdx.x, nb = blockIdx.y, e = blockIdx.z;
    const bool sh = (e >= E_NUM);
    const int m0 = mt * 128;
    const int Me = sh ? 128 : min(cnt[e], CAPC);
    if (m0 >= Me) return;
    const int Mt = min(128, Me - m0);
    const int obase = sh ? (offs[E_NUM] + (e - E_NUM) * 128) : (offs[e] + m0);
    const float* gw = sh ? sgate_w : gate_w + (size_t)e * (H_DIM * I_DIM);
    const float* uw = sh ? sup_w  : up_w  + (size_t)e * (H_DIM * I_DIM);
    const int n0 = nb * 64;

    __shared__ ushort Bls[2 * 2 * 4096];   // [buf][mat][kchunk(8)][n(64)][8] bf16 = 32 KB

    const int tid  = threadIdx.x;
    const int lane = tid & 63, wid = tid >> 6;
    const int wm = wid >> 1, wn = wid & 1;        // 4m x 2n waves
    const int fr = lane & 15, fg = lane >> 4;

    // A: two token rows per lane, fragments straight from global (bf16 xb)
    const int r0 = wm * 32 + fr, r1 = r0 + 16;
    int t0, t1;
    if (sh) { t0 = (e - E_NUM) * 128 + r0; t1 = (e - E_NUM) * 128 + r1; }
    else {
        t0 = (r0 < Mt) ? exp_tok[e * CAPC + m0 + r0] : 0;
        t1 = (r1 < Mt) ? exp_tok[e * CAPC + m0 + r1] : 0;
    }
    const ushort* a0p = xb + (size_t)t0 * H_DIM + fg * 8;
    const ushort* a1p = xb + (size_t)t1 * H_DIM + fg * 8;

    // B staging: thread owns k-pair (2kp,2kp+1) x n-quad q, both matrices
    const int kp = tid >> 4, q = tid & 15;
    const float* gp = gw + (size_t)(2 * kp) * I_DIM + n0 + q * 4;
    const float* up = uw + (size_t)(2 * kp) * I_DIM + n0 + q * 4;
    const int wbe = (kp >> 2) * 512 + (kp & 3) * 2 + q * 32;   // elem offset, j adds 8

    f32x4 accg[2][2], accu[2][2];
    #pragma unroll
    for (int a = 0; a < 2; ++a)
        #pragma unroll
        for (int b = 0; b < 2; ++b) { accg[a][b] = (f32x4)0.f; accu[a][b] = (f32x4)0.f; }

    float4 pg0 = *(const float4*)gp;
    float4 pg1 = *(const float4*)(gp + I_DIM);
    float4 pu0 = *(const float4*)up;
    float4 pu1 = *(const float4*)(up + I_DIM);

    const int NT = H_DIM / 64;
    for (int kt = 0; kt < NT; ++kt) {
        // consume prefetched weights -> bf16 -> LDS (double-buffered)
        float4 g0 = pg0, g1 = pg1, u0 = pu0, u1 = pu1;
        ushort* bw = &Bls[(kt & 1) * 8192 + wbe];
        #pragma unroll
        for (int j = 0; j < 4; ++j) {
            *(unsigned*)&bw[j * 8]        = pk2(((const float*)&g0)[j], ((const float*)&g1)[j]);
            *(unsigned*)&bw[4096 + j * 8] = pk2(((const float*)&u0)[j], ((const float*)&u1)[j]);
        }
        ldsbar();

        // A fragments for this K-tile (gather from L2/L3-hot xb)
        bf16x8 a00 = *(const bf16x8*)&a0p[kt * 64];
        bf16x8 a01 = *(const bf16x8*)&a0p[kt * 64 + 32];
        bf16x8 a10 = *(const bf16x8*)&a1p[kt * 64];
        bf16x8 a11 = *(const bf16x8*)&a1p[kt * 64 + 32];

        // prefetch next K-tile's weights (stays in flight across next barrier)
        if (kt < NT - 1) {
            const float* gn = gp + (size_t)(kt + 1) * 64 * I_DIM;
            const float* un = up + (size_t)(kt + 1) * 64 * I_DIM;
            pg0 = *(const float4*)gn;  pg1 = *(const float4*)(gn + I_DIM);
            pu0 = *(const float4*)un;  pu1 = *(const float4*)(un + I_DIM);
        }

        const ushort* br = &Bls[(kt & 1) * 8192 + fg * 512 + (wn * 32 + fr) * 8];
        #pragma unroll
        for (int ks = 0; ks < 2; ++ks) {
            bf16x8 bg0 = *(const bf16x8*)&br[ks * 2048];
            bf16x8 bg1 = *(const bf16x8*)&br[ks * 2048 + 128];
            bf16x8 bu0 = *(const bf16x8*)&br[4096 + ks * 2048];
            bf16x8 bu1 = *(const bf16x8*)&br[4096 + ks * 2048 + 128];
            bf16x8 aa0 = ks ? a01 : a00;
            bf16x8 aa1 = ks ? a11 : a10;
            accg[0][0] = __builtin_amdgcn_mfma_f32_16x16x32_bf16(aa0, bg0, accg[0][0], 0, 0, 0);
            accg[0][1] = __builtin_amdgcn_mfma_f32_16x16x32_bf16(aa0, bg1, accg[0][1], 0, 0, 0);
            accg[1][0] = __builtin_amdgcn_mfma_f32_16x16x32_bf16(aa1, bg0, accg[1][0], 0, 0, 0);
            accg[1][1] = __builtin_amdgcn_mfma_f32_16x16x32_bf16(aa1, bg1, accg[1][1], 0, 0, 0);
            accu[0][0] = __builtin_amdgcn_mfma_f32_16x16x32_bf16(aa0, bu0, accu[0][0], 0, 0, 0);
            accu[0][1] = __builtin_amdgcn_mfma_f32_16x16x32_bf16(aa0, bu1, accu[0][1], 0, 0, 0);
            accu[1][0] = __builtin_amdgcn_mfma_f32_16x16x32_bf16(aa1, bu0, accu[1][0], 0, 0, 0);
            accu[1][1] = __builtin_amdgcn_mfma_f32_16x16x32_bf16(aa1, bu1, accu[1][1], 0, 0, 0);
        }
    }

    #pragma unroll
    for (int fm = 0; fm < 2; ++fm)
        #pragma unroll
        for (int fn = 0; fn < 2; ++fn)
            #pragma unroll
            for (int r = 0; r < 4; ++r) {
                const int l = wm * 32 + fm * 16 + fg * 4 + r;
                if (l < Mt) {
                    float g = accg[fm][fn][r];
                    float u = accu[fm][fn][r];
                    float h = g / (1.f + expf(-g)) * u;
                    hbuf[(size_t)(obase + l) * I_DIM + n0 + wn * 32 + fn * 16 + fr] = f2bf(h);
                }
            }
}

// ---------------- GEMM 2: down ----------------
// grid: x = mt (2), y = H/64 (16), z = 72
__global__ __launch_bounds__(512) void k_gemm2(
    const ushort* __restrict__ hbuf,
    const float* __restrict__ down_w, const float* __restrict__ sdown_w,
    const int* __restrict__ cnt, const int* __restrict__ offs,
    float* __restrict__ obuf)
{
    const int mt = blockIdx.x, nb = blockIdx.y, e = blockIdx.z;
    const bool sh = (e >= E_NUM);
    const int m0 = mt * 128;
    const int Me = sh ? 128 : min(cnt[e], CAPC);
    if (m0 >= Me) return;
    const int Mt = min(128, Me - m0);
    const int obase = sh ? (offs[E_NUM] + (e - E_NUM) * 128) : (offs[e] + m0);
    const float* dw = sh ? sdown_w : down_w + (size_t)e * (I_DIM * H_DIM);
    const int n0 = nb * 64;

    __shared__ ushort Bls[2 * 4096];   // 16 KB double-buffered

    const int tid  = threadIdx.x;
    const int lane = tid & 63, wid = tid >> 6;
    const int wm = wid >> 1, wn = wid & 1;
    const int fr = lane & 15, fg = lane >> 4;

    const ushort* a0p = hbuf + (size_t)(obase + wm * 32 + fr) * I_DIM + fg * 8;
    const ushort* a1p = a0p + (size_t)16 * I_DIM;

    const int kp = tid >> 4, q = tid & 15;
    const float* gp = dw + (size_t)(2 * kp) * H_DIM + n0 + q * 4;
    const int wbe = (kp >> 2) * 512 + (kp & 3) * 2 + q * 32;

    f32x4 acc[2][2];
    #pragma unroll
    for (int a = 0; a < 2; ++a)
        #pragma unroll
        for (int b = 0; b < 2; ++b) acc[a][b] = (f32x4)0.f;

    float4 pg0 = *(const float4*)gp;
    float4 pg1 = *(const float4*)(gp + H_DIM);

    const int NT = I_DIM / 64;
    for (int kt = 0; kt < NT; ++kt) {
        float4 g0 = pg0, g1 = pg1;
        ushort* bw = &Bls[(kt & 1) * 4096 + wbe];
        #pragma unroll
        for (int j = 0; j < 4; ++j)
            *(unsigned*)&bw[j * 8] = pk2(((const float*)&g0)[j], ((const float*)&g1)[j]);
        ldsbar();

        bf16x8 a00 = *(const bf16x8*)&a0p[kt * 64];
        bf16x8 a01 = *(const bf16x8*)&a0p[kt * 64 + 32];
        bf16x8 a10 = *(const bf16x8*)&a1p[kt * 64];
        bf16x8 a11 = *(const bf16x8*)&a1p[kt * 64 + 32];

        if (kt < NT - 1) {
            const float* gn = gp + (size_t)(kt + 1) * 64 * H_DIM;
            pg0 = *(const float4*)gn;  pg1 = *(const float4*)(gn + H_DIM);
        }

        const ushort* br = &Bls[(kt & 1) * 4096 + fg * 512 + (wn * 32 + fr) * 8];
        #pragma unroll
        for (int ks = 0; ks < 2; ++ks) {
            bf16x8 b0 = *(const bf16x8*)&br[ks * 2048];
            bf16x8 b1 = *(const bf16x8*)&br[ks * 2048 + 128];
            bf16x8 aa0 = ks ? a01 : a00;
            bf16x8 aa1 = ks ? a11 : a10;
            acc[0][0] = __builtin_amdgcn_mfma_f32_16x16x32_bf16(aa0, b0, acc[0][0], 0, 0, 0);
            acc[0][1] = __builtin_amdgcn_mfma_f32_16x16x32_bf16(aa0, b1, acc[0][1], 0, 0, 0);
            acc[1][0] = __builtin_amdgcn_mfma_f32_16x16x32_bf16(aa1, b0, acc[1][0], 0, 0, 0);
            acc[1][1] = __builtin_amdgcn_mfma_f32_16x16x32_bf16(aa1, b1, acc[1][1], 0, 0, 0);
        }
    }

    #pragma unroll
    for (int fm = 0; fm < 2; ++fm)
        #pragma unroll
        for (int fn = 0; fn < 2; ++fn)
            #pragma unroll
            for (int r = 0; r < 4; ++r) {
                const int l = wm * 32 + fm * 16 + fg * 4 + r;
                if (l < Mt)
                    obuf[(size_t)(obase + l) * H_DIM + n0 + wn * 32 + fn * 16 + fr] = acc[fm][fn][r];
            }
}

// ---------------- combine ----------------
__global__ __launch_bounds__(256) void k_combine(
    const float* __restrict__ obuf, const int* __restrict__ offs,
    const int* __restrict__ tslot, const float* __restrict__ tw,
    float* __restrict__ out)
{
    const int t = blockIdx.x;
    __shared__ int   rs[8];
    __shared__ float wss[8];
    if (threadIdx.x < 8) {
        int id = tslot[t * K_TOP + threadIdx.x];
        rs[threadIdx.x]  = offs[id >> 9] + (id & 511);
        wss[threadIdx.x] = tw[t * K_TOP + threadIdx.x];
    }
    __syncthreads();
    const int c = threadIdx.x * 4;
    const int shrow = offs[E_NUM] + t;
    float4 acc = *(const float4*)&obuf[(size_t)shrow * H_DIM + c];
    #pragma unroll
    for (int j = 0; j < 8; ++j) {
        float4 v = *(const float4*)&obuf[(size_t)rs[j] * H_DIM + c];
        float w = wss[j];
        acc.x += w * v.x; acc.y += w * v.y; acc.z += w * v.z; acc.w += w * v.w;
    }
    *(float4*)&out[(size_t)t * H_DIM + c] = acc;
}

extern "C" void kernel_launch(void* const* d_in, const int* in_sizes, int n_in,
                              void* d_out, int out_size, void* d_ws, size_t ws_size,
                              hipStream_t stream)
{
    const float* x       = (const float*)d_in[0];
    const float* rw      = (const float*)d_in[1];
    const float* gate_w  = (const float*)d_in[2];
    const float* up_w    = (const float*)d_in[3];
    const float* down_w  = (const float*)d_in[4];
    const float* sgate_w = (const float*)d_in[5];
    const float* sup_w   = (const float*)d_in[6];
    const float* sdown_w = (const float*)d_in[7];
    float* out = (float*)d_out;

    char* ws = (char*)d_ws;
    int*    cnt     = (int*)(ws + 0);                    // 64 ints
    int*    offs    = (int*)(ws + 256);                  // 65 ints
    int*    exp_tok = (int*)(ws + 1024);                 // 64*512 ints
    int*    tslot   = (int*)(ws + 1024 + 131072);        // 8192 ints
    float*  tw      = (float*)(ws + 1024 + 131072 + 32768);
    ushort* xb      = (ushort*)(ws + (512u << 10));      // 1024x1024 bf16 = 2 MB
    ushort* hbuf    = (ushort*)(ws + (3u << 20));        // 9216 x 512 bf16 ~ 9.44 MB
    float*  obuf    = (float*)(ws + (13u << 20));        // 9216 x 1024 f32 ~ 37.75 MB

    hipMemsetAsync(cnt, 0, 256, stream);
    k_router<<<T_TOK, 256, 0, stream>>>(x, rw, xb, cnt, exp_tok, tslot, tw);
    k_scan<<<1, 64, 0, stream>>>(cnt, offs);
    k_gemm1<<<dim3(2, 8, 72), 512, 0, stream>>>(xb, gate_w, up_w, sgate_w, sup_w,
                                                cnt, offs, exp_tok, hbuf);
    k_gemm2<<<dim3(2, 16, 72), 512, 0, stream>>>(hbuf, down_w, sdown_w, cnt, offs, obuf);
    k_combine<<<T_TOK, 256, 0, stream>>>(obuf, offs, tslot, tw, out);
}

// Round 4
// 541.485 us; speedup vs baseline: 1.0022x; 1.0022x over previous
//
#include <hip/hip_runtime.h>
#include <hip/hip_bf16.h>

#define T_TOK 1024
#define H_DIM 1024
#define E_NUM 64
#define I_DIM 512
#define K_TOP 8
#define TG_NUM 4
#define CAPC 512
#define RSCALE 2.5f

typedef __attribute__((ext_vector_type(8))) short bf16x8;
typedef __attribute__((ext_vector_type(4))) float f32x4;

__device__ __forceinline__ ushort f2bf(float f) {
    union { float f; unsigned u; } v; v.f = f;
    unsigned r = v.u + 0x7fffu + ((v.u >> 16) & 1u);   // RNE
    return (ushort)(r >> 16);
}
__device__ __forceinline__ unsigned pk2(float lo, float hi) {
    return (unsigned)f2bf(lo) | ((unsigned)f2bf(hi) << 16);
}
// raw barrier: LDS visibility only, no vmcnt drain (keeps prefetch loads in flight)
__device__ __forceinline__ void ldsbar() {
    asm volatile("s_waitcnt lgkmcnt(0)" ::: "memory");
    __builtin_amdgcn_s_barrier();
}

// ---------------- router (+ x -> bf16 pre-convert) ----------------
__global__ __launch_bounds__(256) void k_router(
    const float* __restrict__ x, const float* __restrict__ rw,
    ushort* __restrict__ xb,
    int* __restrict__ cnt, int* __restrict__ exp_tok,
    int* __restrict__ tslot, float* __restrict__ tw)
{
    const int t    = blockIdx.x;
    const int lane = threadIdx.x & 63;
    const int w    = threadIdx.x >> 6;

    {
        const float4 v = *(const float4*)&x[(size_t)t * H_DIM + threadIdx.x * 4];
        ushort4 o; o.x = f2bf(v.x); o.y = f2bf(v.y); o.z = f2bf(v.z); o.w = f2bf(v.w);
        *(ushort4*)&xb[(size_t)t * H_DIM + threadIdx.x * 4] = o;
    }

    const float* xp = x + (size_t)t * H_DIM + w * 256;
    const float* wp = rw + (size_t)(w * 256) * E_NUM + lane;
    float acc = 0.f;
    #pragma unroll 8
    for (int i = 0; i < 256; ++i)
        acc += xp[i] * wp[(size_t)i * E_NUM];

    __shared__ float part[4][64];
    part[w][lane] = acc;
    __syncthreads();
    if (threadIdx.x >= 64) return;

    float logit = part[0][lane] + part[1][lane] + part[2][lane] + part[3][lane];
    float score = 1.f / (1.f + expf(-logit));

    float gm = score;
    gm = fmaxf(gm, __shfl_xor(gm, 1));
    gm = fmaxf(gm, __shfl_xor(gm, 2));
    gm = fmaxf(gm, __shfl_xor(gm, 4));
    const int myg = lane >> 3;
    int grank = 0;
    #pragma unroll
    for (int j = 0; j < 8; ++j) {
        float gj = __shfl(gm, j * 8);
        grank += (gj > gm) || (gj == gm && j < myg);
    }
    float masked = (grank < TG_NUM) ? score : 0.f;

    int erank = 0;
    for (int j = 0; j < 64; ++j) {
        float sj = __shfl(masked, j);
        erank += (sj > masked) || (sj == masked && j < lane);
    }
    const bool keep = (erank < K_TOP);

    float kv = keep ? masked : 0.f;
    kv += __shfl_xor(kv, 1);  kv += __shfl_xor(kv, 2);  kv += __shfl_xor(kv, 4);
    kv += __shfl_xor(kv, 8);  kv += __shfl_xor(kv, 16); kv += __shfl_xor(kv, 32);
    const float wgt = masked / fmaxf(kv, 1e-9f) * RSCALE;

    if (keep) {
        int slot = atomicAdd(&cnt[lane], 1);
        if (slot < CAPC) {
            exp_tok[lane * CAPC + slot] = t;
            tslot[t * K_TOP + erank] = (lane << 9) | slot;
            tw[t * K_TOP + erank]    = wgt;
        } else {
            tslot[t * K_TOP + erank] = (lane << 9);
            tw[t * K_TOP + erank]    = 0.f;
        }
    }
}

// ---------------- prefix scan of counts ----------------
__global__ void k_scan(const int* __restrict__ cnt, int* __restrict__ offs)
{
    const int lane = threadIdx.x;   // 64 threads
    int v = min(cnt[lane], CAPC);
    #pragma unroll
    for (int off = 1; off < 64; off <<= 1) {
        int u = __shfl_up(v, off);
        if (lane >= off) v += u;
    }
    offs[lane + 1] = v;
    if (lane == 0) offs[0] = 0;
}

// ---------------- GEMM 1: gate & up + SwiGLU ----------------
// grid: x = mt (2), y = I/64 (8), z = 72 (64 routed + 8 virtual shared chunks)
// LDS B layout (per buf): [mat(2)][kc(8)][n(64)][kt(8)] bf16; write bank = (4q+c)%32 -> 2-way (free)
__global__ __launch_bounds__(512, 4) void k_gemm1(
    const ushort* __restrict__ xb,
    const float* __restrict__ gate_w, const float* __restrict__ up_w,
    const float* __restrict__ sgate_w, const float* __restrict__ sup_w,
    const int* __restrict__ cnt, const int* __restrict__ offs,
    const int* __restrict__ exp_tok,
    ushort* __restrict__ hbuf)
{
    const int mt = blockIdx.x, nb = blockIdx.y, e = blockIdx.z;
    const bool sh = (e >= E_NUM);
    const int m0 = mt * 128;
    const int Me = sh ? 128 : min(cnt[e], CAPC);
    if (m0 >= Me) return;
    const int Mt = min(128, Me - m0);
    const int obase = sh ? (offs[E_NUM] + (e - E_NUM) * 128) : (offs[e] + m0);
    const float* gw = sh ? sgate_w : gate_w + (size_t)e * (H_DIM * I_DIM);
    const float* uw = sh ? sup_w  : up_w  + (size_t)e * (H_DIM * I_DIM);
    const int n0 = nb * 64;

    __shared__ ushort Bls[2 * 8192];   // 32 KB

    const int tid  = threadIdx.x;
    const int lane = tid & 63, wid = tid >> 6;
    const int wm = wid >> 1, wn = wid & 1;        // 4m x 2n waves
    const int fr = lane & 15, fg = lane >> 4;

    // A: two token rows per lane, fragments straight from global (bf16 xb)
    const int r0 = wm * 32 + fr, r1 = r0 + 16;
    int t0, t1;
    if (sh) { t0 = (e - E_NUM) * 128 + r0; t1 = (e - E_NUM) * 128 + r1; }
    else {
        t0 = (r0 < Mt) ? exp_tok[e * CAPC + m0 + r0] : 0;
        t1 = (r1 < Mt) ? exp_tok[e * CAPC + m0 + r1] : 0;
    }
    const ushort* a0p = xb + (size_t)t0 * H_DIM + fg * 8;
    const ushort* a1p = xb + (size_t)t1 * H_DIM + fg * 8;

    // B staging ownership: k-pair (2kp, 2kp+1), columns n0 + q + 16j (j=0..3)
    const int kp = tid >> 4, q = tid & 15;
    const int kc = kp >> 2, c = kp & 3;
    const float* gp  = gw + (size_t)(2 * kp) * I_DIM + n0 + q;
    const float* upp = uw + (size_t)(2 * kp) * I_DIM + n0 + q;
    const int wbase = kc * 512 + q * 8 + c * 2;   // elems; j adds 128; up adds 4096; buf adds 8192

    f32x4 accg[2][2], accu[2][2];
    #pragma unroll
    for (int a = 0; a < 2; ++a)
        #pragma unroll
        for (int b = 0; b < 2; ++b) { accg[a][b] = (f32x4)0.f; accu[a][b] = (f32x4)0.f; }

    float wg0[2][4], wg1[2][4], wu0[2][4], wu1[2][4];   // weight prefetch, depth 2
    bf16x8 av[2][4];                                    // A prefetch, depth 1

#define LOADW1(p, kt) {                                                        \
    const float* g_ = gp  + (size_t)(kt) * 64 * I_DIM;                         \
    const float* u_ = upp + (size_t)(kt) * 64 * I_DIM;                         \
    wg0[p][0]=g_[0];  wg0[p][1]=g_[16]; wg0[p][2]=g_[32]; wg0[p][3]=g_[48];    \
    wg1[p][0]=g_[I_DIM]; wg1[p][1]=g_[I_DIM+16]; wg1[p][2]=g_[I_DIM+32]; wg1[p][3]=g_[I_DIM+48]; \
    wu0[p][0]=u_[0];  wu0[p][1]=u_[16]; wu0[p][2]=u_[32]; wu0[p][3]=u_[48];    \
    wu1[p][0]=u_[I_DIM]; wu1[p][1]=u_[I_DIM+16]; wu1[p][2]=u_[I_DIM+32]; wu1[p][3]=u_[I_DIM+48]; }
#define LOADA1(p, kt) {                                                        \
    av[p][0] = *(const bf16x8*)&a0p[(kt) * 64];                                \
    av[p][1] = *(const bf16x8*)&a0p[(kt) * 64 + 32];                           \
    av[p][2] = *(const bf16x8*)&a1p[(kt) * 64];                                \
    av[p][3] = *(const bf16x8*)&a1p[(kt) * 64 + 32]; }

    LOADW1(0, 0); LOADA1(0, 0); LOADW1(1, 1);

    #pragma unroll
    for (int kt = 0; kt < 16; ++kt) {
        const int p = kt & 1;
        // consume W(kt): cvt -> LDS buf p
        ushort* bw = &Bls[p * 8192 + wbase];
        #pragma unroll
        for (int j = 0; j < 4; ++j) {
            *(unsigned*)&bw[j * 128]        = pk2(wg0[p][j], wg1[p][j]);
            *(unsigned*)&bw[4096 + j * 128] = pk2(wu0[p][j], wu1[p][j]);
        }
        ldsbar();
        // prefetch: W two tiles ahead, A one tile ahead (issue->use crosses a barrier)
        if (kt + 2 < 16) LOADW1(p, kt + 2);
        if (kt + 1 < 16) LOADA1(1 - p, kt + 1);

        const ushort* br = &Bls[p * 8192 + fg * 512 + (wn * 32 + fr) * 8];
        #pragma unroll
        for (int ks = 0; ks < 2; ++ks) {
            bf16x8 bg0 = *(const bf16x8*)&br[ks * 2048];
            bf16x8 bg1 = *(const bf16x8*)&br[ks * 2048 + 128];
            bf16x8 bu0 = *(const bf16x8*)&br[4096 + ks * 2048];
            bf16x8 bu1 = *(const bf16x8*)&br[4096 + ks * 2048 + 128];
            bf16x8 aa0 = ks ? av[p][1] : av[p][0];
            bf16x8 aa1 = ks ? av[p][3] : av[p][2];
            accg[0][0] = __builtin_amdgcn_mfma_f32_16x16x32_bf16(aa0, bg0, accg[0][0], 0, 0, 0);
            accg[0][1] = __builtin_amdgcn_mfma_f32_16x16x32_bf16(aa0, bg1, accg[0][1], 0, 0, 0);
            accg[1][0] = __builtin_amdgcn_mfma_f32_16x16x32_bf16(aa1, bg0, accg[1][0], 0, 0, 0);
            accg[1][1] = __builtin_amdgcn_mfma_f32_16x16x32_bf16(aa1, bg1, accg[1][1], 0, 0, 0);
            accu[0][0] = __builtin_amdgcn_mfma_f32_16x16x32_bf16(aa0, bu0, accu[0][0], 0, 0, 0);
            accu[0][1] = __builtin_amdgcn_mfma_f32_16x16x32_bf16(aa0, bu1, accu[0][1], 0, 0, 0);
            accu[1][0] = __builtin_amdgcn_mfma_f32_16x16x32_bf16(aa1, bu0, accu[1][0], 0, 0, 0);
            accu[1][1] = __builtin_amdgcn_mfma_f32_16x16x32_bf16(aa1, bu1, accu[1][1], 0, 0, 0);
        }
    }
#undef LOADW1
#undef LOADA1

    #pragma unroll
    for (int fm = 0; fm < 2; ++fm)
        #pragma unroll
        for (int fn = 0; fn < 2; ++fn)
            #pragma unroll
            for (int r = 0; r < 4; ++r) {
                const int l = wm * 32 + fm * 16 + fg * 4 + r;
                if (l < Mt) {
                    float g = accg[fm][fn][r];
                    float u = accu[fm][fn][r];
                    float h = g / (1.f + expf(-g)) * u;
                    hbuf[(size_t)(obase + l) * I_DIM + n0 + wn * 32 + fn * 16 + fr] = f2bf(h);
                }
            }
}

// ---------------- GEMM 2: down ----------------
// grid: x = mt (2), y = H/64 (16), z = 72
__global__ __launch_bounds__(512, 4) void k_gemm2(
    const ushort* __restrict__ hbuf,
    const float* __restrict__ down_w, const float* __restrict__ sdown_w,
    const int* __restrict__ cnt, const int* __restrict__ offs,
    float* __restrict__ obuf)
{
    const int mt = blockIdx.x, nb = blockIdx.y, e = blockIdx.z;
    const bool sh = (e >= E_NUM);
    const int m0 = mt * 128;
    const int Me = sh ? 128 : min(cnt[e], CAPC);
    if (m0 >= Me) return;
    const int Mt = min(128, Me - m0);
    const int obase = sh ? (offs[E_NUM] + (e - E_NUM) * 128) : (offs[e] + m0);
    const float* dw = sh ? sdown_w : down_w + (size_t)e * (I_DIM * H_DIM);
    const int n0 = nb * 64;

    __shared__ ushort Bls[2 * 4096];   // 16 KB

    const int tid  = threadIdx.x;
    const int lane = tid & 63, wid = tid >> 6;
    const int wm = wid >> 1, wn = wid & 1;
    const int fr = lane & 15, fg = lane >> 4;

    const ushort* a0p = hbuf + (size_t)(obase + wm * 32 + fr) * I_DIM + fg * 8;
    const ushort* a1p = a0p + (size_t)16 * I_DIM;

    const int kp = tid >> 4, q = tid & 15;
    const int kc = kp >> 2, c = kp & 3;
    const float* dp = dw + (size_t)(2 * kp) * H_DIM + n0 + q;
    const int wbase = kc * 512 + q * 8 + c * 2;

    f32x4 acc[2][2];
    #pragma unroll
    for (int a = 0; a < 2; ++a)
        #pragma unroll
        for (int b = 0; b < 2; ++b) acc[a][b] = (f32x4)0.f;

    float wd0[2][4], wd1[2][4];
    bf16x8 av[2][4];

#define LOADW2(p, kt) {                                                        \
    const float* d_ = dp + (size_t)(kt) * 64 * H_DIM;                          \
    wd0[p][0]=d_[0];  wd0[p][1]=d_[16]; wd0[p][2]=d_[32]; wd0[p][3]=d_[48];    \
    wd1[p][0]=d_[H_DIM]; wd1[p][1]=d_[H_DIM+16]; wd1[p][2]=d_[H_DIM+32]; wd1[p][3]=d_[H_DIM+48]; }
#define LOADA2(p, kt) {                                                        \
    av[p][0] = *(const bf16x8*)&a0p[(kt) * 64];                                \
    av[p][1] = *(const bf16x8*)&a0p[(kt) * 64 + 32];                           \
    av[p][2] = *(const bf16x8*)&a1p[(kt) * 64];                                \
    av[p][3] = *(const bf16x8*)&a1p[(kt) * 64 + 32]; }

    LOADW2(0, 0); LOADA2(0, 0); LOADW2(1, 1);

    #pragma unroll
    for (int kt = 0; kt < 8; ++kt) {
        const int p = kt & 1;
        ushort* bw = &Bls[p * 4096 + wbase];
        #pragma unroll
        for (int j = 0; j < 4; ++j)
            *(unsigned*)&bw[j * 128] = pk2(wd0[p][j], wd1[p][j]);
        ldsbar();
        if (kt + 2 < 8) LOADW2(p, kt + 2);
        if (kt + 1 < 8) LOADA2(1 - p, kt + 1);

        const ushort* br = &Bls[p * 4096 + fg * 512 + (wn * 32 + fr) * 8];
        #pragma unroll
        for (int ks = 0; ks < 2; ++ks) {
            bf16x8 b0 = *(const bf16x8*)&br[ks * 2048];
            bf16x8 b1 = *(const bf16x8*)&br[ks * 2048 + 128];
            bf16x8 aa0 = ks ? av[p][1] : av[p][0];
            bf16x8 aa1 = ks ? av[p][3] : av[p][2];
            acc[0][0] = __builtin_amdgcn_mfma_f32_16x16x32_bf16(aa0, b0, acc[0][0], 0, 0, 0);
            acc[0][1] = __builtin_amdgcn_mfma_f32_16x16x32_bf16(aa0, b1, acc[0][1], 0, 0, 0);
            acc[1][0] = __builtin_amdgcn_mfma_f32_16x16x32_bf16(aa1, b0, acc[1][0], 0, 0, 0);
            acc[1][1] = __builtin_amdgcn_mfma_f32_16x16x32_bf16(aa1, b1, acc[1][1], 0, 0, 0);
        }
    }
#undef LOADW2
#undef LOADA2

    #pragma unroll
    for (int fm = 0; fm < 2; ++fm)
        #pragma unroll
        for (int fn = 0; fn < 2; ++fn)
            #pragma unroll
            for (int r = 0; r < 4; ++r) {
                const int l = wm * 32 + fm * 16 + fg * 4 + r;
                if (l < Mt)
                    obuf[(size_t)(obase + l) * H_DIM + n0 + wn * 32 + fn * 16 + fr] = acc[fm][fn][r];
            }
}

// ---------------- combine ----------------
__global__ __launch_bounds__(256) void k_combine(
    const float* __restrict__ obuf, const int* __restrict__ offs,
    const int* __restrict__ tslot, const float* __restrict__ tw,
    float* __restrict__ out)
{
    const int t = blockIdx.x;
    __shared__ int   rs[8];
    __shared__ float wss[8];
    if (threadIdx.x < 8) {
        int id = tslot[t * K_TOP + threadIdx.x];
        rs[threadIdx.x]  = offs[id >> 9] + (id & 511);
        wss[threadIdx.x] = tw[t * K_TOP + threadIdx.x];
    }
    __syncthreads();
    const int c = threadIdx.x * 4;
    const int shrow = offs[E_NUM] + t;
    float4 acc = *(const float4*)&obuf[(size_t)shrow * H_DIM + c];
    #pragma unroll
    for (int j = 0; j < 8; ++j) {
        float4 v = *(const float4*)&obuf[(size_t)rs[j] * H_DIM + c];
        float w = wss[j];
        acc.x += w * v.x; acc.y += w * v.y; acc.z += w * v.z; acc.w += w * v.w;
    }
    *(float4*)&out[(size_t)t * H_DIM + c] = acc;
}

extern "C" void kernel_launch(void* const* d_in, const int* in_sizes, int n_in,
                              void* d_out, int out_size, void* d_ws, size_t ws_size,
                              hipStream_t stream)
{
    const float* x       = (const float*)d_in[0];
    const float* rw      = (const float*)d_in[1];
    const float* gate_w  = (const float*)d_in[2];
    const float* up_w    = (const float*)d_in[3];
    const float* down_w  = (const float*)d_in[4];
    const float* sgate_w = (const float*)d_in[5];
    const float* sup_w   = (const float*)d_in[6];
    const float* sdown_w = (const float*)d_in[7];
    float* out = (float*)d_out;

    char* ws = (char*)d_ws;
    int*    cnt     = (int*)(ws + 0);                    // 64 ints
    int*    offs    = (int*)(ws + 256);                  // 65 ints
    int*    exp_tok = (int*)(ws + 1024);                 // 64*512 ints
    int*    tslot   = (int*)(ws + 1024 + 131072);        // 8192 ints
    float*  tw      = (float*)(ws + 1024 + 131072 + 32768);
    ushort* xb      = (ushort*)(ws + (512u << 10));      // 1024x1024 bf16 = 2 MB
    ushort* hbuf    = (ushort*)(ws + (3u << 20));        // 9216 x 512 bf16 ~ 9.44 MB
    float*  obuf    = (float*)(ws + (13u << 20));        // 9216 x 1024 f32 ~ 37.75 MB

    hipMemsetAsync(cnt, 0, 256, stream);
    k_router<<<T_TOK, 256, 0, stream>>>(x, rw, xb, cnt, exp_tok, tslot, tw);
    k_scan<<<1, 64, 0, stream>>>(cnt, offs);
    k_gemm1<<<dim3(2, 8, 72), 512, 0, stream>>>(xb, gate_w, up_w, sgate_w, sup_w,
                                                cnt, offs, exp_tok, hbuf);
    k_gemm2<<<dim3(2, 16, 72), 512, 0, stream>>>(hbuf, down_w, sdown_w, cnt, offs, obuf);
    k_combine<<<T_TOK, 256, 0, stream>>>(obuf, offs, tslot, tw, out);
}

// Round 7
// 513.066 us; speedup vs baseline: 1.0577x; 1.0554x over previous
//
#include <hip/hip_runtime.h>
#include <hip/hip_bf16.h>

#define T_TOK 1024
#define H_DIM 1024
#define E_NUM 64
#define I_DIM 512
#define K_TOP 8
#define TG_NUM 4
#define CAPC 512
#define RSCALE 2.5f

typedef __attribute__((ext_vector_type(8))) short bf16x8;
typedef __attribute__((ext_vector_type(4))) float f32x4;

#define MFMA_BF16 __builtin_amdgcn_mfma_f32_16x16x32_bf16

__device__ __forceinline__ ushort f2bf(float f) {
    union { float f; unsigned u; } v; v.f = f;
    unsigned r = v.u + 0x7fffu + ((v.u >> 16) & 1u);   // RNE
    return (ushort)(r >> 16);
}
__device__ __forceinline__ unsigned pk2(float lo, float hi) {
    return (unsigned)f2bf(lo) | ((unsigned)f2bf(hi) << 16);
}
// raw barrier: LDS visibility only, no vmcnt drain (keeps prefetch loads in flight)
__device__ __forceinline__ void ldsbar() {
    asm volatile("s_waitcnt lgkmcnt(0)" ::: "memory");
    __builtin_amdgcn_s_barrier();
}

// ---------------- router (+ x -> bf16 pre-convert) ----------------
__global__ __launch_bounds__(256) void k_router(
    const float* __restrict__ x, const float* __restrict__ rw,
    ushort* __restrict__ xb,
    int* __restrict__ cnt, int* __restrict__ exp_tok,
    int* __restrict__ tslot, float* __restrict__ tw)
{
    const int t    = blockIdx.x;
    const int lane = threadIdx.x & 63;
    const int w    = threadIdx.x >> 6;

    {
        const float4 v = *(const float4*)&x[(size_t)t * H_DIM + threadIdx.x * 4];
        ushort4 o; o.x = f2bf(v.x); o.y = f2bf(v.y); o.z = f2bf(v.z); o.w = f2bf(v.w);
        *(ushort4*)&xb[(size_t)t * H_DIM + threadIdx.x * 4] = o;
    }

    const float* xp = x + (size_t)t * H_DIM + w * 256;
    const float* wp = rw + (size_t)(w * 256) * E_NUM + lane;
    float acc = 0.f;
    #pragma unroll 8
    for (int i = 0; i < 256; ++i)
        acc += xp[i] * wp[(size_t)i * E_NUM];

    __shared__ float part[4][64];
    part[w][lane] = acc;
    __syncthreads();
    if (threadIdx.x >= 64) return;

    float logit = part[0][lane] + part[1][lane] + part[2][lane] + part[3][lane];
    float score = 1.f / (1.f + expf(-logit));

    float gm = score;
    gm = fmaxf(gm, __shfl_xor(gm, 1));
    gm = fmaxf(gm, __shfl_xor(gm, 2));
    gm = fmaxf(gm, __shfl_xor(gm, 4));
    const int myg = lane >> 3;
    int grank = 0;
    #pragma unroll
    for (int j = 0; j < 8; ++j) {
        float gj = __shfl(gm, j * 8);
        grank += (gj > gm) || (gj == gm && j < myg);
    }
    float masked = (grank < TG_NUM) ? score : 0.f;

    int erank = 0;
    for (int j = 0; j < 64; ++j) {
        float sj = __shfl(masked, j);
        erank += (sj > masked) || (sj == masked && j < lane);
    }
    const bool keep = (erank < K_TOP);

    float kv = keep ? masked : 0.f;
    kv += __shfl_xor(kv, 1);  kv += __shfl_xor(kv, 2);  kv += __shfl_xor(kv, 4);
    kv += __shfl_xor(kv, 8);  kv += __shfl_xor(kv, 16); kv += __shfl_xor(kv, 32);
    const float wgt = masked / fmaxf(kv, 1e-9f) * RSCALE;

    if (keep) {
        int slot = atomicAdd(&cnt[lane], 1);
        if (slot < CAPC) {
            exp_tok[lane * CAPC + slot] = t;
            tslot[t * K_TOP + erank] = (lane << 9) | slot;
            tw[t * K_TOP + erank]    = wgt;
        } else {
            tslot[t * K_TOP + erank] = (lane << 9);
            tw[t * K_TOP + erank]    = 0.f;
        }
    }
}

// ---------------- prefix scan of counts ----------------
__global__ void k_scan(const int* __restrict__ cnt, int* __restrict__ offs)
{
    const int lane = threadIdx.x;   // 64 threads
    int v = min(cnt[lane], CAPC);
    #pragma unroll
    for (int off = 1; off < 64; off <<= 1) {
        int u = __shfl_up(v, off);
        if (lane >= off) v += u;
    }
    offs[lane + 1] = v;
    if (lane == 0) offs[0] = 0;
}

// ---------------- GEMM 1: gate & up + SwiGLU ----------------
// grid: x = I/64 (8), y = 72 (64 routed + 8 virtual shared chunks); BM=128, BK=32
// LDS per buf: [mat(2)][kc(4)][n(64)][kk(8)] bf16 = 8 KB; 2 bufs = 16 KB total
__global__ __launch_bounds__(512, 4) void k_gemm1(
    const ushort* __restrict__ xb,
    const float* __restrict__ gate_w, const float* __restrict__ up_w,
    const float* __restrict__ sgate_w, const float* __restrict__ sup_w,
    const int* __restrict__ cnt, const int* __restrict__ offs,
    const int* __restrict__ exp_tok,
    ushort* __restrict__ hbuf)
{
    const int nb = blockIdx.x, e = blockIdx.y;
    const bool sh = (e >= E_NUM);
    const int Me = sh ? 128 : min(cnt[e], CAPC);
    const int ebase = sh ? (offs[E_NUM] + (e - E_NUM) * 128) : offs[e];
    const float* gw = sh ? sgate_w : gate_w + (size_t)e * (H_DIM * I_DIM);
    const float* uw = sh ? sup_w  : up_w  + (size_t)e * (H_DIM * I_DIM);
    const int n0 = nb * 64;

    __shared__ ushort Bls[2 * 4096];   // 16 KB

    const int tid  = threadIdx.x;
    const int lane = tid & 63, wid = tid >> 6;
    const int wm = wid >> 1, wn = wid & 1;        // 4m x 2n waves over 128x64
    const int fr = lane & 15, fg = lane >> 4;

    // staging ownership: 512 threads; k-pair kp = tid>>5 (rows 2kp,2kp+1), cols 2q,2q+1
    const int kp = tid >> 5, q = tid & 31;
    const int kc = kp >> 2, c = kp & 3;
    const float* gp  = gw + (size_t)(2 * kp) * I_DIM + n0 + 2 * q;
    const float* upp = uw + (size_t)(2 * kp) * I_DIM + n0 + 2 * q;
    const int wb = kc * 512 + q * 16 + c * 2;     // elem offset; +8 for col+1; +2048 for up-mat

#define LW1(S, kt) { const float* g_ = gp  + (size_t)(kt) * 32 * I_DIM;        \
                     const float* u_ = upp + (size_t)(kt) * 32 * I_DIM;        \
                     ga##S = *(const float2*)g_;  gb##S = *(const float2*)(g_ + I_DIM); \
                     ua##S = *(const float2*)u_;  ub##S = *(const float2*)(u_ + I_DIM); }
#define LA1(S, kt) { a0##S = *(const bf16x8*)&a0p[(kt) * 32];                  \
                     a1##S = *(const bf16x8*)&a1p[(kt) * 32]; }
#define SW1(S, bo) { ushort* bw = &Bls[(bo) + wb];                             \
                     *(unsigned*)&bw[0]        = pk2(ga##S.x, gb##S.x);        \
                     *(unsigned*)&bw[8]        = pk2(ga##S.y, gb##S.y);        \
                     *(unsigned*)&bw[2048]     = pk2(ua##S.x, ub##S.x);        \
                     *(unsigned*)&bw[2048 + 8] = pk2(ua##S.y, ub##S.y); }
#define MM1(A0, A1, bo) {                                                      \
    const ushort* br = &Bls[(bo) + fg * 512 + (wn * 32 + fr) * 8];             \
    bf16x8 bg0 = *(const bf16x8*)&br[0];                                       \
    bf16x8 bg1 = *(const bf16x8*)&br[128];                                     \
    bf16x8 bu0 = *(const bf16x8*)&br[2048];                                    \
    bf16x8 bu1 = *(const bf16x8*)&br[2176];                                    \
    accg00 = MFMA_BF16(A0, bg0, accg00, 0, 0, 0);                              \
    accg01 = MFMA_BF16(A0, bg1, accg01, 0, 0, 0);                              \
    accg10 = MFMA_BF16(A1, bg0, accg10, 0, 0, 0);                              \
    accg11 = MFMA_BF16(A1, bg1, accg11, 0, 0, 0);                              \
    accu00 = MFMA_BF16(A0, bu0, accu00, 0, 0, 0);                              \
    accu01 = MFMA_BF16(A0, bu1, accu01, 0, 0, 0);                              \
    accu10 = MFMA_BF16(A1, bu0, accu10, 0, 0, 0);                              \
    accu11 = MFMA_BF16(A1, bu1, accu11, 0, 0, 0); }

    for (int m0 = 0; m0 < Me; m0 += 128) {
        const int Mt = min(128, Me - m0);
        const int obase = ebase + m0;
        const int r0 = wm * 32 + fr, r1 = r0 + 16;
        int t0, t1;
        if (sh) { t0 = (e - E_NUM) * 128 + r0; t1 = t0 + 16; }
        else {
            t0 = (r0 < Mt) ? exp_tok[e * CAPC + m0 + r0] : 0;
            t1 = (r1 < Mt) ? exp_tok[e * CAPC + m0 + r1] : 0;
        }
        const ushort* a0p = xb + (size_t)t0 * H_DIM + fg * 8;
        const ushort* a1p = xb + (size_t)t1 * H_DIM + fg * 8;

        f32x4 accg00 = (f32x4)0.f, accg01 = (f32x4)0.f, accg10 = (f32x4)0.f, accg11 = (f32x4)0.f;
        f32x4 accu00 = (f32x4)0.f, accu01 = (f32x4)0.f, accu10 = (f32x4)0.f, accu11 = (f32x4)0.f;
        float2 gaE, gbE, uaE, ubE, gaO, gbO, uaO, ubO;
        bf16x8 a0E, a1E, a0O, a1O;

        LW1(E, 0); LA1(E, 0); LW1(O, 1);

        for (int it = 0; it < 16; ++it) {
            const int kt = it * 2;
            SW1(E, 0);
            ldsbar();
            if (it < 15) LW1(E, kt + 2);
            LA1(O, kt + 1);
            MM1(a0E, a1E, 0);
            SW1(O, 4096);
            ldsbar();
            if (it < 15) { LW1(O, kt + 3); LA1(E, kt + 2); }
            MM1(a0O, a1O, 4096);
        }

#define EPI1(AG, AU, rowofs, colofs)                                           \
        _Pragma("unroll")                                                      \
        for (int r = 0; r < 4; ++r) {                                          \
            const int l = wm * 32 + (rowofs) + fg * 4 + r;                     \
            if (l < Mt) {                                                      \
                const float g = AG[r], u = AU[r];                              \
                const float h = g / (1.f + __expf(-g)) * u;                    \
                hbuf[(size_t)(obase + l) * I_DIM + n0 + wn * 32 + (colofs) + fr] = f2bf(h); } }
        EPI1(accg00, accu00, 0, 0);  EPI1(accg01, accu01, 0, 16);
        EPI1(accg10, accu10, 16, 0); EPI1(accg11, accu11, 16, 16);
#undef EPI1
    }
#undef LW1
#undef LA1
#undef SW1
#undef MM1
}

// ---------------- GEMM 2: down ----------------
// grid: x = H/64 (16), y = 72; BM=128, BK=32
__global__ __launch_bounds__(512, 4) void k_gemm2(
    const ushort* __restrict__ hbuf,
    const float* __restrict__ down_w, const float* __restrict__ sdown_w,
    const int* __restrict__ cnt, const int* __restrict__ offs,
    float* __restrict__ obuf)
{
    const int nb = blockIdx.x, e = blockIdx.y;
    const bool sh = (e >= E_NUM);
    const int Me = sh ? 128 : min(cnt[e], CAPC);
    const int ebase = sh ? (offs[E_NUM] + (e - E_NUM) * 128) : offs[e];
    const float* dw = sh ? sdown_w : down_w + (size_t)e * (I_DIM * H_DIM);
    const int n0 = nb * 64;

    __shared__ ushort Bls[2 * 2048];   // 8 KB

    const int tid  = threadIdx.x;
    const int lane = tid & 63, wid = tid >> 6;
    const int wm = wid >> 1, wn = wid & 1;
    const int fr = lane & 15, fg = lane >> 4;

    const int kp = tid >> 5, q = tid & 31;
    const int kc = kp >> 2, c = kp & 3;
    const float* dp = dw + (size_t)(2 * kp) * H_DIM + n0 + 2 * q;
    const int wb = kc * 512 + q * 16 + c * 2;

#define LW2(S, kt) { const float* d_ = dp + (size_t)(kt) * 32 * H_DIM;         \
                     da##S = *(const float2*)d_;  db##S = *(const float2*)(d_ + H_DIM); }
#define LA2(S, kt) { a0##S = *(const bf16x8*)&a0p[(kt) * 32];                  \
                     a1##S = *(const bf16x8*)&a1p[(kt) * 32]; }
#define SW2(S, bo) { ushort* bw = &Bls[(bo) + wb];                             \
                     *(unsigned*)&bw[0] = pk2(da##S.x, db##S.x);               \
                     *(unsigned*)&bw[8] = pk2(da##S.y, db##S.y); }
#define MM2(A0, A1, bo) {                                                      \
    const ushort* br = &Bls[(bo) + fg * 512 + (wn * 32 + fr) * 8];             \
    bf16x8 b0 = *(const bf16x8*)&br[0];                                        \
    bf16x8 b1 = *(const bf16x8*)&br[128];                                      \
    ac00 = MFMA_BF16(A0, b0, ac00, 0, 0, 0);                                   \
    ac01 = MFMA_BF16(A0, b1, ac01, 0, 0, 0);                                   \
    ac10 = MFMA_BF16(A1, b0, ac10, 0, 0, 0);                                   \
    ac11 = MFMA_BF16(A1, b1, ac11, 0, 0, 0); }

    for (int m0 = 0; m0 < Me; m0 += 128) {
        const int Mt = min(128, Me - m0);
        const int obase = ebase + m0;
        const ushort* a0p = hbuf + (size_t)(obase + wm * 32 + fr) * I_DIM + fg * 8;
        const ushort* a1p = a0p + (size_t)16 * I_DIM;

        f32x4 ac00 = (f32x4)0.f, ac01 = (f32x4)0.f, ac10 = (f32x4)0.f, ac11 = (f32x4)0.f;
        float2 daE, dbE, daO, dbO;
        bf16x8 a0E, a1E, a0O, a1O;

        LW2(E, 0); LA2(E, 0); LW2(O, 1);

        for (int it = 0; it < 8; ++it) {
            const int kt = it * 2;
            SW2(E, 0);
            ldsbar();
            if (it < 7) LW2(E, kt + 2);
            LA2(O, kt + 1);
            MM2(a0E, a1E, 0);
            SW2(O, 2048);
            ldsbar();
            if (it < 7) { LW2(O, kt + 3); LA2(E, kt + 2); }
            MM2(a0O, a1O, 2048);
        }

#define EPO2(AC, rowofs, colofs)                                               \
        _Pragma("unroll")                                                      \
        for (int r = 0; r < 4; ++r) {                                          \
            const int l = wm * 32 + (rowofs) + fg * 4 + r;                     \
            if (l < Mt)                                                        \
                obuf[(size_t)(obase + l) * H_DIM + n0 + wn * 32 + (colofs) + fr] = AC[r]; }
        EPO2(ac00, 0, 0);  EPO2(ac01, 0, 16);
        EPO2(ac10, 16, 0); EPO2(ac11, 16, 16);
#undef EPO2
    }
#undef LW2
#undef LA2
#undef SW2
#undef MM2
}

// ---------------- combine ----------------
__global__ __launch_bounds__(256) void k_combine(
    const float* __restrict__ obuf, const int* __restrict__ offs,
    const int* __restrict__ tslot, const float* __restrict__ tw,
    float* __restrict__ out)
{
    const int t = blockIdx.x;
    __shared__ int   rs[8];
    __shared__ float wss[8];
    if (threadIdx.x < 8) {
        int id = tslot[t * K_TOP + threadIdx.x];
        rs[threadIdx.x]  = offs[id >> 9] + (id & 511);
        wss[threadIdx.x] = tw[t * K_TOP + threadIdx.x];
    }
    __syncthreads();
    const int c = threadIdx.x * 4;
    const int shrow = offs[E_NUM] + t;
    float4 acc = *(const float4*)&obuf[(size_t)shrow * H_DIM + c];
    #pragma unroll
    for (int j = 0; j < 8; ++j) {
        float4 v = *(const float4*)&obuf[(size_t)rs[j] * H_DIM + c];
        float w = wss[j];
        acc.x += w * v.x; acc.y += w * v.y; acc.z += w * v.z; acc.w += w * v.w;
    }
    *(float4*)&out[(size_t)t * H_DIM + c] = acc;
}

extern "C" void kernel_launch(void* const* d_in, const int* in_sizes, int n_in,
                              void* d_out, int out_size, void* d_ws, size_t ws_size,
                              hipStream_t stream)
{
    const float* x       = (const float*)d_in[0];
    const float* rw      = (const float*)d_in[1];
    const float* gate_w  = (const float*)d_in[2];
    const float* up_w    = (const float*)d_in[3];
    const float* down_w  = (const float*)d_in[4];
    const float* sgate_w = (const float*)d_in[5];
    const float* sup_w   = (const float*)d_in[6];
    const float* sdown_w = (const float*)d_in[7];
    float* out = (float*)d_out;

    char* ws = (char*)d_ws;
    int*    cnt     = (int*)(ws + 0);                    // 64 ints
    int*    offs    = (int*)(ws + 256);                  // 65 ints
    int*    exp_tok = (int*)(ws + 1024);                 // 64*512 ints
    int*    tslot   = (int*)(ws + 1024 + 131072);        // 8192 ints
    float*  tw      = (float*)(ws + 1024 + 131072 + 32768);
    ushort* xb      = (ushort*)(ws + (512u << 10));      // 1024x1024 bf16 = 2 MB
    ushort* hbuf    = (ushort*)(ws + (3u << 20));        // 9216 x 512 bf16 ~ 9.44 MB
    float*  obuf    = (float*)(ws + (13u << 20));        // 9216 x 1024 f32 ~ 37.75 MB

    hipMemsetAsync(cnt, 0, 256, stream);
    k_router<<<T_TOK, 256, 0, stream>>>(x, rw, xb, cnt, exp_tok, tslot, tw);
    k_scan<<<1, 64, 0, stream>>>(cnt, offs);
    k_gemm1<<<dim3(8, 72), 512, 0, stream>>>(xb, gate_w, up_w, sgate_w, sup_w,
                                             cnt, offs, exp_tok, hbuf);
    k_gemm2<<<dim3(16, 72), 512, 0, stream>>>(hbuf, down_w, sdown_w, cnt, offs, obuf);
    k_combine<<<T_TOK, 256, 0, stream>>>(obuf, offs, tslot, tw, out);
}